// Round 10
// baseline (70.423 us; speedup 1.0000x reference)
//
#include <hip/hip_runtime.h>
#include <cstdint>

#define NCLS 13
#define SMAX 10
#define PTHRESH 0.05f
#define FPS_SEG 4        // blocks per (b,c)
#define FPS_T 1024       // threads per FPS block (16 waves)
#define FPS_PPT 16       // points per thread: 4*1024*16 = 65536
#define NSLOT 4          // one record per block per step
#define BCPAD 32         // padded bc dim: all blocks of a bc share bid%32
#define GABLK 256        // k_setup blocks per batch (N/256)
#define BB 2             // batch
#define SLOT_DWORDS (BB * NCLS * SMAX * NSLOT * 2)

// Exact (un-fused) squared distance, matching numpy's ((dx*dx + dy*dy) + dz*dz) in f32.
__device__ __forceinline__ float d2f(float ax, float ay, float az,
                                     float bx, float by, float bz) {
    float dx = ax - bx;
    float dy = ay - by;
    float dz = az - bz;
    return __fadd_rn(__fadd_rn(__fmul_rn(dx, dx), __fmul_rn(dy, dy)), __fmul_rn(dz, dz));
}

// Monotone mapping float -> uint32. Never 0 for non-NaN input => key==0 means "empty".
__device__ __forceinline__ unsigned int fmono(float f) {
    unsigned int u = __float_as_uint(f);
    return (u & 0x80000000u) ? ~u : (u | 0x80000000u);
}

// Kernel A: class softmax, packed coords (float4) + per-point class-validity bitmask (u16),
// per-block partial counts/first-index (full overwrite, no atomics), FPS slot zeroing.
__global__ void k_setup(const float* __restrict__ logits, const float* __restrict__ pts,
                        const float* __restrict__ offs, float* __restrict__ probs,
                        float4* __restrict__ xyzw, unsigned short* __restrict__ vmask,
                        unsigned int* __restrict__ pcnt, unsigned int* __restrict__ pfst,
                        unsigned int* __restrict__ slots32, int N) {
    int b = blockIdx.y;
    int n = blockIdx.x * blockDim.x + threadIdx.x;
    int t = threadIdx.x;
    __shared__ unsigned int sC[NCLS], sF[NCLS];
    if (t < NCLS) { sC[t] = 0u; sF[t] = 0xFFFFFFFFu; }
    __syncthreads();

    // zero FPS slots (every call: graph replays leave stale nonzero keys behind)
    if (b == 0) {
        for (unsigned int i = blockIdx.x * blockDim.x + t; i < SLOT_DWORDS;
             i += GABLK * 256)
            slots32[i] = 0u;
    }

    if (n < N) {
        size_t bn = (size_t)b * N + n;
        const float* L = logits + bn * NCLS;
        float v[NCLS];
        float mx = -INFINITY;
#pragma unroll
        for (int c = 0; c < NCLS; ++c) { v[c] = L[c]; mx = fmaxf(mx, v[c]); }
        float s = 0.f;
#pragma unroll
        for (int c = 0; c < NCLS; ++c) { v[c] = expf(v[c] - mx); s += v[c]; }
        int lane = t & 63;
        int wave_base = n - lane;
        unsigned int msk = 0;
#pragma unroll
        for (int c = 0; c < NCLS; ++c) {
            float p = v[c] / s;
            probs[((size_t)b * NCLS + c) * N + n] = p;
            bool valid = p > PTHRESH;
            if (valid) msk |= (1u << c);
            unsigned long long m = __ballot(valid);
            if (lane == 0 && m) {
                atomicAdd(&sC[c], (unsigned int)__popcll(m));
                atomicMin(&sF[c], (unsigned int)(wave_base + __ffsll(m) - 1));
            }
        }
        float x = pts[bn * 3 + 0] + offs[bn * 3 + 0];
        float y = pts[bn * 3 + 1] + offs[bn * 3 + 1];
        float z = pts[bn * 3 + 2] + offs[bn * 3 + 2];
        xyzw[bn] = make_float4(x, y, z, 0.f);
        vmask[bn] = (unsigned short)msk;
    }
    __syncthreads();
    if (t < NCLS) {
        pcnt[(b * NCLS + t) * GABLK + blockIdx.x] = sC[t];
        pfst[(b * NCLS + t) * GABLK + blockIdx.x] = sF[t];
    }
}

// Kernel B: deterministic FPS. 4 blocks x 1024 threads per (b,c). Per step (2 barriers):
// wave butterfly argmax -> s_keys[par] -> B1 -> wave0: reduce 16 keys, lane0 publishes
// block record, lanes 0-3 poll the 4-slot line with s_sleep backoff (one coalesced
// request/iteration), butterfly-4, s_win[par] -> B2 -> all read s_win[par].
// Parity double-buffering removes round 8's third barrier; wave0-only polling removes
// round 9's all-wave contention (4096 tight spinners -> 16 lanes at sleep cadence).
__global__ __launch_bounds__(FPS_T, 1) void k_fps(
    const float4* __restrict__ xyzw, const unsigned short* __restrict__ vmask,
    const unsigned int* __restrict__ pcnt, const unsigned int* __restrict__ pfst,
    int* __restrict__ nseeds, float* __restrict__ seedxyz,
    unsigned long long* __restrict__ slots, int N) {
    int bid = blockIdx.x;
    int bc = bid & (BCPAD - 1);
    int g = bid >> 5;             // segment 0..3
    if (bc >= BB * NCLS) return;  // padding blocks
    int b = bc / NCLS;
    int c = bc - b * NCLS;
    int t = threadIdx.x, lane = t & 63, w = t >> 6;

    // Reduce per-block partials (each wave redundantly; identical ops -> identical result)
    const unsigned int* pc = pcnt + (size_t)bc * GABLK;
    const unsigned int* pf = pfst + (size_t)bc * GABLK;
    uint4 c4 = *(const uint4*)(pc + lane * 4);
    uint4 f4 = *(const uint4*)(pf + lane * 4);
    unsigned int cnt = c4.x + c4.y + c4.z + c4.w;
    unsigned int fst = min(min(f4.x, f4.y), min(f4.z, f4.w));
#pragma unroll
    for (int off = 1; off < 64; off <<= 1) {
        cnt += __shfl_xor(cnt, off, 64);
        fst = min(fst, __shfl_xor(fst, off, 64));
    }
    int ns = min(SMAX, min((int)cnt / 50, (int)cnt));
    if (g == 0 && t == 0) nseeds[bc] = ns;
    if (ns == 0) return;

    const float4* P4 = xyzw + (size_t)b * N;
    const unsigned short* VM = vmask + (size_t)b * N;

    int base = g * (FPS_T * FPS_PPT) + t;
    float X[FPS_PPT], Y[FPS_PPT], Z[FPS_PPT], m[FPS_PPT];
    unsigned int vm = 0;
#pragma unroll
    for (int j = 0; j < FPS_PPT; ++j) {
        int n = base + (j << 10);
        float4 q = P4[n];
        X[j] = q.x; Y[j] = q.y; Z[j] = q.z;
        if ((VM[n] >> c) & 1) vm |= (1u << j);
        m[j] = INFINITY;
    }

    int st = (int)fst;
    float4 q0 = P4[st];
    float cx = q0.x, cy = q0.y, cz = q0.z;
    if (g == 0 && t == 0) {
        float* sd = seedxyz + (size_t)bc * SMAX * 3;
        sd[0] = cx; sd[1] = cy; sd[2] = cz;
    }

    __shared__ unsigned long long s_keys[2][FPS_T / 64];
    __shared__ unsigned long long s_win[2];

    for (int s = 1; s < ns; ++s) {
        float best = -INFINITY;
        int bidx = 0;
#pragma unroll
        for (int j = 0; j < FPS_PPT; ++j) {   // ascending n => first-occurrence tiebreak
            int n = base + (j << 10);
            float d2 = d2f(X[j], Y[j], Z[j], cx, cy, cz);
            float add = ((vm >> j) & 1u) ? 0.0f : -INFINITY;
            float nm = fminf(m[j], __fadd_rn(d2, add));
            m[j] = nm;
            if (nm > best) { best = nm; bidx = n; }
        }
        unsigned long long key =
            ((unsigned long long)fmono(best) << 32) | (unsigned int)(~(unsigned int)bidx);
#pragma unroll
        for (int off = 1; off < 64; off <<= 1) {
            unsigned long long ok = __shfl_xor(key, off, 64);
            if (ok > key) key = ok;
        }
        int par = s & 1;
        if (lane == 0) s_keys[par][w] = key;
        __syncthreads();   // B1

        if (w == 0) {
            unsigned long long bk = (lane < FPS_T / 64) ? s_keys[par][lane] : 0ULL;
#pragma unroll
            for (int off = 1; off < FPS_T / 64; off <<= 1) {
                unsigned long long ok = __shfl_xor(bk, off, FPS_T / 64);
                if (ok > bk) bk = ok;
            }
            unsigned long long* sl = slots + ((size_t)bc * SMAX + s) * NSLOT;
            if (lane == 0)
                __hip_atomic_store(&sl[g], bk, __ATOMIC_RELAXED, __HIP_MEMORY_SCOPE_AGENT);
            asm volatile("" ::: "memory");
            unsigned long long kk = 0ULL;
            while (true) {
                if (lane < NSLOT && kk == 0ULL)
                    kk = __hip_atomic_load(&sl[lane], __ATOMIC_RELAXED,
                                           __HIP_MEMORY_SCOPE_AGENT);
                if (__all(kk != 0ULL || lane >= NSLOT)) break;
                __builtin_amdgcn_s_sleep(1);
            }
            asm volatile("" ::: "memory");
#pragma unroll
            for (int off = 1; off < NSLOT; off <<= 1) {
                unsigned long long ok = __shfl_xor(kk, off, NSLOT);
                if (ok > kk) kk = ok;
            }
            if (lane == 0) s_win[par] = kk;
        }
        __syncthreads();   // B2

        int widx = (int)(~(unsigned int)s_win[par]);
        float4 qw = P4[widx];
        cx = qw.x; cy = qw.y; cz = qw.z;
        if (g == 0 && t == 0) {
            float* sd = seedxyz + ((size_t)bc * SMAX + s) * 3;
            sd[0] = cx; sd[1] = cy; sd[2] = cz;
        }
    }
}

// Kernel C: 512-thread block owns 128 points (2 per lane). Wave w handles classes
// {w, w+8} in pass 1 (gd + partial sumexp -> LDS), rows k==w (mod 8) in pass 2 with
// float2 output stores (512B per wave-row write).
__global__ __launch_bounds__(512) void k_out(
    const float* __restrict__ probs, const float4* __restrict__ xyzw,
    const int* __restrict__ nseeds, const float* __restrict__ seedxyz,
    float* __restrict__ out, int N) {
    int b = blockIdx.y;
    int t = threadIdx.x;
    int lane = t & 63;
    int wv = t >> 6;
    int n0 = blockIdx.x * 128 + lane * 2;

    __shared__ float S[NCLS * SMAX * 3];
    __shared__ int NSs[NCLS];
    __shared__ float gdS[NCLS][128];
    __shared__ float psum[8][128];
    if (t < NCLS * SMAX * 3) S[t] = seedxyz[(size_t)b * NCLS * SMAX * 3 + t];
    if (t >= 448 && t < 448 + NCLS) NSs[t - 448] = nseeds[b * NCLS + (t - 448)];
    __syncthreads();

    float4 q0 = xyzw[(size_t)b * N + n0];
    float4 q1 = xyzw[(size_t)b * N + n0 + 1];

    const float kinv = 22.2222222f;   // 1/0.045
    float ps0 = 0.f, ps1 = 0.f;
#pragma unroll
    for (int c = wv; c < NCLS; c += 8) {
        int ns = NSs[c];
        float gdv0 = 0.f, gdv1 = 0.f;
        if (ns > 0) {
            float2 pv = *(const float2*)(probs + ((size_t)b * NCLS + c) * N + n0);
            if (pv.x > PTHRESH) {
                float wb[SMAX]; float sw = 0.f;
#pragma unroll
                for (int s = 0; s < SMAX; ++s) {
                    wb[s] = 0.f;
                    if (s < ns) {
                        const float* sd = &S[(c * SMAX + s) * 3];
                        float d2 = d2f(q0.x, q0.y, q0.z, sd[0], sd[1], sd[2]);
                        wb[s] = __expf(-d2 * kinv);
                        sw += wb[s];
                    }
                }
                gdv0 = __fdividef(pv.x, sw + 1e-8f);
#pragma unroll
                for (int s = 0; s < SMAX; ++s)
                    if (s < ns) ps0 += __expf(10.f * wb[s] * gdv0);
            } else {
                ps0 += (float)ns;   // exp(0)=1 per valid seed, exact
            }
            if (pv.y > PTHRESH) {
                float wb[SMAX]; float sw = 0.f;
#pragma unroll
                for (int s = 0; s < SMAX; ++s) {
                    wb[s] = 0.f;
                    if (s < ns) {
                        const float* sd = &S[(c * SMAX + s) * 3];
                        float d2 = d2f(q1.x, q1.y, q1.z, sd[0], sd[1], sd[2]);
                        wb[s] = __expf(-d2 * kinv);
                        sw += wb[s];
                    }
                }
                gdv1 = __fdividef(pv.y, sw + 1e-8f);
#pragma unroll
                for (int s = 0; s < SMAX; ++s)
                    if (s < ns) ps1 += __expf(10.f * wb[s] * gdv1);
            } else {
                ps1 += (float)ns;
            }
        }
        gdS[c][lane * 2] = gdv0;
        gdS[c][lane * 2 + 1] = gdv1;
    }
    psum[wv][lane * 2] = ps0;
    psum[wv][lane * 2 + 1] = ps1;
    __syncthreads();

    float tot0 = 0.f, tot1 = 0.f;
#pragma unroll
    for (int w = 0; w < 8; ++w) {
        tot0 += psum[w][lane * 2];
        tot1 += psum[w][lane * 2 + 1];
    }
    float inv0 = __fdividef(1.f, tot0);
    float inv1 = __fdividef(1.f, tot1);

    float* ob = out + (size_t)b * (NCLS * SMAX) * N + n0;
#pragma unroll
    for (int k = 0; k < NCLS * SMAX; k += 8) {
        int kk = k + wv;
        if (kk >= NCLS * SMAX) break;
        int c = kk / SMAX, s = kk - c * SMAX;
        float o0 = 0.f, o1 = 0.f;
        if (s < NSs[c]) {
            float g0 = gdS[c][lane * 2];
            float g1 = gdS[c][lane * 2 + 1];
            const float* sd = &S[(c * SMAX + s) * 3];
            if (g0 > 0.f) {
                float d2 = d2f(q0.x, q0.y, q0.z, sd[0], sd[1], sd[2]);
                o0 = __expf(10.f * __expf(-d2 * kinv) * g0) * inv0;
            } else {
                o0 = inv0;
            }
            if (g1 > 0.f) {
                float d2 = d2f(q1.x, q1.y, q1.z, sd[0], sd[1], sd[2]);
                o1 = __expf(10.f * __expf(-d2 * kinv) * g1) * inv1;
            } else {
                o1 = inv1;
            }
        }
        float2 st; st.x = o0; st.y = o1;
        *(float2*)(ob + (size_t)kk * N) = st;
    }
}

extern "C" void kernel_launch(void* const* d_in, const int* in_sizes, int n_in,
                              void* d_out, int out_size, void* d_ws, size_t ws_size,
                              hipStream_t stream) {
    const float* logits = (const float*)d_in[0];
    const float* pts    = (const float*)d_in[1];
    const float* offs   = (const float*)d_in[2];
    float* out = (float*)d_out;

    const int B = BB;
    const int BN = in_sizes[0] / NCLS;   // B*N
    const int N = BN / B;                // 65536

    // Workspace layout
    char* w = (char*)d_ws;
    size_t off = 0;
    auto take = [&](size_t bytes) -> void* {
        void* p = w + off;
        off = (off + bytes + 255) & ~(size_t)255;
        return p;
    };
    float* probs   = (float*)take((size_t)B * NCLS * N * sizeof(float));
    float4* xyzw   = (float4*)take((size_t)B * N * sizeof(float4));
    unsigned short* vmsk = (unsigned short*)take((size_t)B * N * sizeof(unsigned short));
    float* seedxyz = (float*)take((size_t)B * NCLS * SMAX * 3 * sizeof(float));
    unsigned int* pcnt = (unsigned int*)take((size_t)B * NCLS * GABLK * sizeof(unsigned int));
    unsigned int* pfst = (unsigned int*)take((size_t)B * NCLS * GABLK * sizeof(unsigned int));
    int* nseeds        = (int*)take(B * NCLS * sizeof(int));
    unsigned long long* slots =
        (unsigned long long*)take((size_t)B * NCLS * SMAX * NSLOT * sizeof(unsigned long long));

    dim3 gA((N + 255) / 256, B);   // == (GABLK, B)
    k_setup<<<gA, 256, 0, stream>>>(logits, pts, offs, probs, xyzw, vmsk,
                                    pcnt, pfst, (unsigned int*)slots, N);

    k_fps<<<BCPAD * FPS_SEG, FPS_T, 0, stream>>>(xyzw, vmsk, pcnt, pfst,
                                                 nseeds, seedxyz, slots, N);

    dim3 gC(N / 128, B);
    k_out<<<gC, 512, 0, stream>>>(probs, xyzw, nseeds, seedxyz, out, N);
}

// Round 11
// 69.133 us; speedup vs baseline: 1.0187x; 1.0187x over previous
//
#include <hip/hip_runtime.h>
#include <cstdint>

#define NCLS 13
#define SMAX 10
#define PTHRESH 0.05f
#define FPS_SEG 8        // blocks per (b,c)
#define FPS_T 512        // threads per FPS block (8 waves)
#define FPS_PPT 16       // points per thread: 8*512*16 = 65536
#define NSLOT 8          // one record per block per step
#define BCPAD 32         // padded bc dim: all 8 blocks of a bc share bid%32
#define GABLK 256        // k_setup blocks per batch (N/256)
#define BB 2             // batch
#define OUT_T 256        // k_out threads (4 waves, 64-point tile)
#define SLOT_DWORDS (BB * NCLS * SMAX * NSLOT * 2)

// Exact (un-fused) squared distance, matching numpy's ((dx*dx + dy*dy) + dz*dz) in f32.
__device__ __forceinline__ float d2f(float ax, float ay, float az,
                                     float bx, float by, float bz) {
    float dx = ax - bx;
    float dy = ay - by;
    float dz = az - bz;
    return __fadd_rn(__fadd_rn(__fmul_rn(dx, dx), __fmul_rn(dy, dy)), __fmul_rn(dz, dz));
}

// Monotone mapping float -> uint32. Never 0 for non-NaN input => key==0 means "empty".
__device__ __forceinline__ unsigned int fmono(float f) {
    unsigned int u = __float_as_uint(f);
    return (u & 0x80000000u) ? ~u : (u | 0x80000000u);
}

// Kernel A: class softmax, packed coords (float4) + per-point class-validity bitmask (u16),
// per-block partial counts/first-index (full overwrite, no atomics), FPS slot zeroing.
__global__ void k_setup(const float* __restrict__ logits, const float* __restrict__ pts,
                        const float* __restrict__ offs, float* __restrict__ probs,
                        float4* __restrict__ xyzw, unsigned short* __restrict__ vmask,
                        unsigned int* __restrict__ pcnt, unsigned int* __restrict__ pfst,
                        unsigned int* __restrict__ slots32, int N) {
    int b = blockIdx.y;
    int n = blockIdx.x * blockDim.x + threadIdx.x;
    int t = threadIdx.x;
    __shared__ unsigned int sC[NCLS], sF[NCLS];
    if (t < NCLS) { sC[t] = 0u; sF[t] = 0xFFFFFFFFu; }
    __syncthreads();

    // zero FPS slots (every call: graph replays leave stale nonzero keys behind)
    if (b == 0) {
        for (unsigned int i = blockIdx.x * blockDim.x + t; i < SLOT_DWORDS;
             i += GABLK * 256)
            slots32[i] = 0u;
    }

    if (n < N) {
        size_t bn = (size_t)b * N + n;
        const float* L = logits + bn * NCLS;
        float v[NCLS];
        float mx = -INFINITY;
#pragma unroll
        for (int c = 0; c < NCLS; ++c) { v[c] = L[c]; mx = fmaxf(mx, v[c]); }
        float s = 0.f;
#pragma unroll
        for (int c = 0; c < NCLS; ++c) { v[c] = expf(v[c] - mx); s += v[c]; }
        int lane = t & 63;
        int wave_base = n - lane;
        unsigned int msk = 0;
#pragma unroll
        for (int c = 0; c < NCLS; ++c) {
            float p = v[c] / s;
            probs[((size_t)b * NCLS + c) * N + n] = p;
            bool valid = p > PTHRESH;
            if (valid) msk |= (1u << c);
            unsigned long long m = __ballot(valid);
            if (lane == 0 && m) {
                atomicAdd(&sC[c], (unsigned int)__popcll(m));
                atomicMin(&sF[c], (unsigned int)(wave_base + __ffsll(m) - 1));
            }
        }
        float x = pts[bn * 3 + 0] + offs[bn * 3 + 0];
        float y = pts[bn * 3 + 1] + offs[bn * 3 + 1];
        float z = pts[bn * 3 + 2] + offs[bn * 3 + 2];
        xyzw[bn] = make_float4(x, y, z, 0.f);
        vmask[bn] = (unsigned short)msk;
    }
    __syncthreads();
    if (t < NCLS) {
        pcnt[(b * NCLS + t) * GABLK + blockIdx.x] = sC[t];
        pfst[(b * NCLS + t) * GABLK + blockIdx.x] = sF[t];
    }
}

// Kernel B: deterministic FPS (round-9 config — measured best). 8 blocks x 512 threads
// per (b,c). Per step (ONE barrier): wave butterfly argmax -> s_keys[parity] -> barrier
// -> wave0 reduces 8 keys, lane0 publishes block record -> ALL waves poll the 8-slot
// line (8-lane coalesced relaxed load) -> butterfly-8 + broadcast -> winner coords
// from immutable xyzw (single dwordx4).
__global__ __launch_bounds__(FPS_T, 1) void k_fps(
    const float4* __restrict__ xyzw, const unsigned short* __restrict__ vmask,
    const unsigned int* __restrict__ pcnt, const unsigned int* __restrict__ pfst,
    int* __restrict__ nseeds, float* __restrict__ seedxyz,
    unsigned long long* __restrict__ slots, int N) {
    int bid = blockIdx.x;
    int bc = bid & (BCPAD - 1);
    int g = bid >> 5;             // segment 0..7
    if (bc >= BB * NCLS) return;  // padding blocks
    int b = bc / NCLS;
    int c = bc - b * NCLS;
    int t = threadIdx.x, lane = t & 63, w = t >> 6;

    // Reduce per-block partials (each wave redundantly; identical ops -> identical result)
    const unsigned int* pc = pcnt + (size_t)bc * GABLK;
    const unsigned int* pf = pfst + (size_t)bc * GABLK;
    uint4 c4 = *(const uint4*)(pc + lane * 4);
    uint4 f4 = *(const uint4*)(pf + lane * 4);
    unsigned int cnt = c4.x + c4.y + c4.z + c4.w;
    unsigned int fst = min(min(f4.x, f4.y), min(f4.z, f4.w));
#pragma unroll
    for (int off = 1; off < 64; off <<= 1) {
        cnt += __shfl_xor(cnt, off, 64);
        fst = min(fst, __shfl_xor(fst, off, 64));
    }
    int ns = min(SMAX, min((int)cnt / 50, (int)cnt));
    if (g == 0 && t == 0) nseeds[bc] = ns;
    if (ns == 0) return;

    const float4* P4 = xyzw + (size_t)b * N;
    const unsigned short* VM = vmask + (size_t)b * N;

    int base = g * (FPS_T * FPS_PPT) + t;
    float X[FPS_PPT], Y[FPS_PPT], Z[FPS_PPT], m[FPS_PPT];
    unsigned int vm = 0;
#pragma unroll
    for (int j = 0; j < FPS_PPT; ++j) {
        int n = base + (j << 9);
        float4 q = P4[n];
        X[j] = q.x; Y[j] = q.y; Z[j] = q.z;
        if ((VM[n] >> c) & 1) vm |= (1u << j);
        m[j] = INFINITY;
    }

    int st = (int)fst;
    float4 q0 = P4[st];
    float cx = q0.x, cy = q0.y, cz = q0.z;
    if (g == 0 && t == 0) {
        float* sd = seedxyz + (size_t)bc * SMAX * 3;
        sd[0] = cx; sd[1] = cy; sd[2] = cz;
    }

    __shared__ unsigned long long s_keys[2][FPS_T / 64];

    for (int s = 1; s < ns; ++s) {
        float best = -INFINITY;
        int bidx = 0;
#pragma unroll
        for (int j = 0; j < FPS_PPT; ++j) {   // ascending n => first-occurrence tiebreak
            int n = base + (j << 9);
            float d2 = d2f(X[j], Y[j], Z[j], cx, cy, cz);
            float add = ((vm >> j) & 1u) ? 0.0f : -INFINITY;
            float nm = fminf(m[j], __fadd_rn(d2, add));
            m[j] = nm;
            if (nm > best) { best = nm; bidx = n; }
        }
        unsigned long long key =
            ((unsigned long long)fmono(best) << 32) | (unsigned int)(~(unsigned int)bidx);
#pragma unroll
        for (int off = 1; off < 64; off <<= 1) {
            unsigned long long ok = __shfl_xor(key, off, 64);
            if (ok > key) key = ok;
        }
        int par = s & 1;
        if (lane == 0) s_keys[par][w] = key;
        __syncthreads();

        unsigned long long* sl = slots + ((size_t)bc * SMAX + s) * NSLOT;
        if (w == 0) {
            unsigned long long bk = (lane < 8) ? s_keys[par][lane] : 0ULL;
#pragma unroll
            for (int off = 1; off < 8; off <<= 1) {
                unsigned long long ok = __shfl_xor(bk, off, 8);
                if (ok > bk) bk = ok;
            }
            if (lane == 0)
                __hip_atomic_store(&sl[g], bk, __ATOMIC_RELAXED, __HIP_MEMORY_SCOPE_AGENT);
        }
        asm volatile("" ::: "memory");
        unsigned long long kk = 0ULL;
        while (true) {
            if (lane < NSLOT && kk == 0ULL)
                kk = __hip_atomic_load(&sl[lane], __ATOMIC_RELAXED,
                                       __HIP_MEMORY_SCOPE_AGENT);
            if (__all(kk != 0ULL || lane >= NSLOT)) break;
        }
        asm volatile("" ::: "memory");
#pragma unroll
        for (int off = 1; off < 8; off <<= 1) {
            unsigned long long ok = __shfl_xor(kk, off, 8);
            if (ok > kk) kk = ok;
        }
        kk = __shfl(kk, 0, 64);   // broadcast winner to all 64 lanes

        int widx = (int)(~(unsigned int)kk);
        float4 qw = P4[widx];
        cx = qw.x; cy = qw.y; cz = qw.z;
        if (g == 0 && t == 0) {
            float* sd = seedxyz + ((size_t)bc * SMAX + s) * 3;
            sd[0] = cx; sd[1] = cy; sd[2] = cz;
        }
    }
}

// Kernel C: 256-thread block owns 64 points (lane=point). Wave w handles classes
// {w, w+4, w+8, w+12} in pass 1, computing gd AND caching e=exp(10*w*gd) per live row
// in LDS E[130][64]. Pass 2 (rows kk==w mod 4) is then a pure LDS read + mul + store:
// no d2f/exp recompute (halves VALU, cuts transcendentals 3x vs round 9).
__global__ __launch_bounds__(OUT_T) void k_out(
    const float* __restrict__ probs, const float4* __restrict__ xyzw,
    const int* __restrict__ nseeds, const float* __restrict__ seedxyz,
    float* __restrict__ out, int N) {
    int b = blockIdx.y;
    int t = threadIdx.x;
    int lane = t & 63;
    int wv = t >> 6;     // wave 0..3
    int n = blockIdx.x * 64 + lane;

    __shared__ float S[NCLS * SMAX * 3];
    __shared__ int NSs[NCLS];
    __shared__ float gdS[NCLS][64];
    __shared__ float psum[4][64];
    __shared__ float E[NCLS * SMAX][64];
    for (int i = t; i < NCLS * SMAX * 3; i += OUT_T)
        S[i] = seedxyz[(size_t)b * NCLS * SMAX * 3 + i];
    if (t < NCLS) NSs[t] = nseeds[b * NCLS + t];
    __syncthreads();

    float4 q = xyzw[(size_t)b * N + n];

    const float kinv = 22.2222222f;   // 1/0.045
    float ps = 0.f;
    for (int c = wv; c < NCLS; c += 4) {
        int ns = NSs[c];
        float gdv = 0.f;
        if (ns > 0) {
            float pv = probs[((size_t)b * NCLS + c) * N + n];
            if (pv > PTHRESH) {
                float wb[SMAX];
                float sw = 0.f;
#pragma unroll
                for (int s = 0; s < SMAX; ++s) {
                    wb[s] = 0.f;
                    if (s < ns) {
                        const float* sd = &S[(c * SMAX + s) * 3];
                        float d2 = d2f(q.x, q.y, q.z, sd[0], sd[1], sd[2]);
                        wb[s] = __expf(-d2 * kinv);
                        sw += wb[s];
                    }
                }
                gdv = __fdividef(pv, sw + 1e-8f);
#pragma unroll
                for (int s = 0; s < SMAX; ++s)
                    if (s < ns) {
                        float e = __expf(10.f * wb[s] * gdv);
                        E[c * SMAX + s][lane] = e;
                        ps += e;
                    }
            } else {
                ps += (float)ns;   // exp(0)=1 per valid seed, exact
            }
        }
        gdS[c][lane] = gdv;
    }
    psum[wv][lane] = ps;
    __syncthreads();

    float tot = psum[0][lane] + psum[1][lane] + psum[2][lane] + psum[3][lane];
    float inv = __fdividef(1.f, tot);

    float* ob = out + (size_t)b * (NCLS * SMAX) * N + n;
    for (int kk = wv; kk < NCLS * SMAX; kk += 4) {
        int c = kk / SMAX, s = kk - c * SMAX;
        float o = 0.f;
        if (s < NSs[c]) {
            float gdv = gdS[c][lane];
            o = (gdv > 0.f) ? E[kk][lane] * inv : inv;
        }
        ob[(size_t)kk * N] = o;
    }
}

extern "C" void kernel_launch(void* const* d_in, const int* in_sizes, int n_in,
                              void* d_out, int out_size, void* d_ws, size_t ws_size,
                              hipStream_t stream) {
    const float* logits = (const float*)d_in[0];
    const float* pts    = (const float*)d_in[1];
    const float* offs   = (const float*)d_in[2];
    float* out = (float*)d_out;

    const int B = BB;
    const int BN = in_sizes[0] / NCLS;   // B*N
    const int N = BN / B;                // 65536

    // Workspace layout
    char* w = (char*)d_ws;
    size_t off = 0;
    auto take = [&](size_t bytes) -> void* {
        void* p = w + off;
        off = (off + bytes + 255) & ~(size_t)255;
        return p;
    };
    float* probs   = (float*)take((size_t)B * NCLS * N * sizeof(float));
    float4* xyzw   = (float4*)take((size_t)B * N * sizeof(float4));
    unsigned short* vmsk = (unsigned short*)take((size_t)B * N * sizeof(unsigned short));
    float* seedxyz = (float*)take((size_t)B * NCLS * SMAX * 3 * sizeof(float));
    unsigned int* pcnt = (unsigned int*)take((size_t)B * NCLS * GABLK * sizeof(unsigned int));
    unsigned int* pfst = (unsigned int*)take((size_t)B * NCLS * GABLK * sizeof(unsigned int));
    int* nseeds        = (int*)take(B * NCLS * sizeof(int));
    unsigned long long* slots =
        (unsigned long long*)take((size_t)B * NCLS * SMAX * NSLOT * sizeof(unsigned long long));

    dim3 gA((N + 255) / 256, B);   // == (GABLK, B)
    k_setup<<<gA, 256, 0, stream>>>(logits, pts, offs, probs, xyzw, vmsk,
                                    pcnt, pfst, (unsigned int*)slots, N);

    k_fps<<<BCPAD * FPS_SEG, FPS_T, 0, stream>>>(xyzw, vmsk, pcnt, pfst,
                                                 nseeds, seedxyz, slots, N);

    dim3 gC(N / 64, B);
    k_out<<<gC, OUT_T, 0, stream>>>(probs, xyzw, nseeds, seedxyz, out, N);
}

// Round 12
// 64.371 us; speedup vs baseline: 1.0940x; 1.0740x over previous
//
#include <hip/hip_runtime.h>
#include <cstdint>

#define NCLS 13
#define SMAX 10
#define PTHRESH 0.05f
#define FPS_SEG 8        // blocks per (b,c)
#define FPS_T 512        // threads per FPS block (8 waves)
#define FPS_PPT 16       // points per thread: 8*512*16 = 65536
#define NSLOT 8          // one record per block per step
#define BCPAD 32         // padded bc dim: all 8 blocks of a bc share bid%32
#define GABLK 256        // k_setup blocks per batch (N/256)
#define BB 2             // batch
#define OUT_T 512        // k_out threads (8 waves, 128-point tile, 2 pts/lane)
#define SLOT_DWORDS (BB * NCLS * SMAX * NSLOT * 2)

// Exact (un-fused) squared distance, matching numpy's ((dx*dx + dy*dy) + dz*dz) in f32.
__device__ __forceinline__ float d2f(float ax, float ay, float az,
                                     float bx, float by, float bz) {
    float dx = ax - bx;
    float dy = ay - by;
    float dz = az - bz;
    return __fadd_rn(__fadd_rn(__fmul_rn(dx, dx), __fmul_rn(dy, dy)), __fmul_rn(dz, dz));
}

// Monotone mapping float -> uint32. Never 0 for non-NaN input => key==0 means "empty".
__device__ __forceinline__ unsigned int fmono(float f) {
    unsigned int u = __float_as_uint(f);
    return (u & 0x80000000u) ? ~u : (u | 0x80000000u);
}

// Kernel A: class softmax (accurate expf -> discrete decisions), packed coords (float4),
// per-point class-validity bitmask (u16), per-block partial counts/first-index, slot
// zeroing. probs are NOT materialized (k_out re-derives pv; k_fps uses vmask only).
__global__ void k_setup(const float* __restrict__ logits, const float* __restrict__ pts,
                        const float* __restrict__ offs,
                        float4* __restrict__ xyzw, unsigned short* __restrict__ vmask,
                        unsigned int* __restrict__ pcnt, unsigned int* __restrict__ pfst,
                        unsigned int* __restrict__ slots32, int N) {
    int b = blockIdx.y;
    int n = blockIdx.x * blockDim.x + threadIdx.x;
    int t = threadIdx.x;
    __shared__ unsigned int sC[NCLS], sF[NCLS];
    if (t < NCLS) { sC[t] = 0u; sF[t] = 0xFFFFFFFFu; }
    __syncthreads();

    // zero FPS slots (every call: graph replays leave stale nonzero keys behind)
    if (b == 0) {
        for (unsigned int i = blockIdx.x * blockDim.x + t; i < SLOT_DWORDS;
             i += GABLK * 256)
            slots32[i] = 0u;
    }

    if (n < N) {
        size_t bn = (size_t)b * N + n;
        const float* L = logits + bn * NCLS;
        float v[NCLS];
        float mx = -INFINITY;
#pragma unroll
        for (int c = 0; c < NCLS; ++c) { v[c] = L[c]; mx = fmaxf(mx, v[c]); }
        float s = 0.f;
#pragma unroll
        for (int c = 0; c < NCLS; ++c) { v[c] = expf(v[c] - mx); s += v[c]; }
        int lane = t & 63;
        int wave_base = n - lane;
        unsigned int msk = 0;
#pragma unroll
        for (int c = 0; c < NCLS; ++c) {
            float p = v[c] / s;
            bool valid = p > PTHRESH;
            if (valid) msk |= (1u << c);
            unsigned long long m = __ballot(valid);
            if (lane == 0 && m) {
                atomicAdd(&sC[c], (unsigned int)__popcll(m));
                atomicMin(&sF[c], (unsigned int)(wave_base + __ffsll(m) - 1));
            }
        }
        float x = pts[bn * 3 + 0] + offs[bn * 3 + 0];
        float y = pts[bn * 3 + 1] + offs[bn * 3 + 1];
        float z = pts[bn * 3 + 2] + offs[bn * 3 + 2];
        xyzw[bn] = make_float4(x, y, z, 0.f);
        vmask[bn] = (unsigned short)msk;
    }
    __syncthreads();
    if (t < NCLS) {
        pcnt[(b * NCLS + t) * GABLK + blockIdx.x] = sC[t];
        pfst[(b * NCLS + t) * GABLK + blockIdx.x] = sF[t];
    }
}

// Kernel B: deterministic FPS (round-9 config — measured best). 8 blocks x 512 threads
// per (b,c). Per step (ONE barrier): wave butterfly argmax -> s_keys[parity] -> barrier
// -> wave0 reduces 8 keys, lane0 publishes block record -> ALL waves poll the 8-slot
// line (8-lane coalesced relaxed load) -> butterfly-8 + broadcast -> winner coords
// from immutable xyzw (single dwordx4).
__global__ __launch_bounds__(FPS_T, 1) void k_fps(
    const float4* __restrict__ xyzw, const unsigned short* __restrict__ vmask,
    const unsigned int* __restrict__ pcnt, const unsigned int* __restrict__ pfst,
    int* __restrict__ nseeds, float* __restrict__ seedxyz,
    unsigned long long* __restrict__ slots, int N) {
    int bid = blockIdx.x;
    int bc = bid & (BCPAD - 1);
    int g = bid >> 5;             // segment 0..7
    if (bc >= BB * NCLS) return;  // padding blocks
    int b = bc / NCLS;
    int c = bc - b * NCLS;
    int t = threadIdx.x, lane = t & 63, w = t >> 6;

    // Reduce per-block partials (each wave redundantly; identical ops -> identical result)
    const unsigned int* pc = pcnt + (size_t)bc * GABLK;
    const unsigned int* pf = pfst + (size_t)bc * GABLK;
    uint4 c4 = *(const uint4*)(pc + lane * 4);
    uint4 f4 = *(const uint4*)(pf + lane * 4);
    unsigned int cnt = c4.x + c4.y + c4.z + c4.w;
    unsigned int fst = min(min(f4.x, f4.y), min(f4.z, f4.w));
#pragma unroll
    for (int off = 1; off < 64; off <<= 1) {
        cnt += __shfl_xor(cnt, off, 64);
        fst = min(fst, __shfl_xor(fst, off, 64));
    }
    int ns = min(SMAX, min((int)cnt / 50, (int)cnt));
    if (g == 0 && t == 0) nseeds[bc] = ns;
    if (ns == 0) return;

    const float4* P4 = xyzw + (size_t)b * N;
    const unsigned short* VM = vmask + (size_t)b * N;

    int base = g * (FPS_T * FPS_PPT) + t;
    float X[FPS_PPT], Y[FPS_PPT], Z[FPS_PPT], m[FPS_PPT];
    unsigned int vm = 0;
#pragma unroll
    for (int j = 0; j < FPS_PPT; ++j) {
        int n = base + (j << 9);
        float4 q = P4[n];
        X[j] = q.x; Y[j] = q.y; Z[j] = q.z;
        if ((VM[n] >> c) & 1) vm |= (1u << j);
        m[j] = INFINITY;
    }

    int st = (int)fst;
    float4 q0 = P4[st];
    float cx = q0.x, cy = q0.y, cz = q0.z;
    if (g == 0 && t == 0) {
        float* sd = seedxyz + (size_t)bc * SMAX * 3;
        sd[0] = cx; sd[1] = cy; sd[2] = cz;
    }

    __shared__ unsigned long long s_keys[2][FPS_T / 64];

    for (int s = 1; s < ns; ++s) {
        float best = -INFINITY;
        int bidx = 0;
#pragma unroll
        for (int j = 0; j < FPS_PPT; ++j) {   // ascending n => first-occurrence tiebreak
            int n = base + (j << 9);
            float d2 = d2f(X[j], Y[j], Z[j], cx, cy, cz);
            float add = ((vm >> j) & 1u) ? 0.0f : -INFINITY;
            float nm = fminf(m[j], __fadd_rn(d2, add));
            m[j] = nm;
            if (nm > best) { best = nm; bidx = n; }
        }
        unsigned long long key =
            ((unsigned long long)fmono(best) << 32) | (unsigned int)(~(unsigned int)bidx);
#pragma unroll
        for (int off = 1; off < 64; off <<= 1) {
            unsigned long long ok = __shfl_xor(key, off, 64);
            if (ok > key) key = ok;
        }
        int par = s & 1;
        if (lane == 0) s_keys[par][w] = key;
        __syncthreads();

        unsigned long long* sl = slots + ((size_t)bc * SMAX + s) * NSLOT;
        if (w == 0) {
            unsigned long long bk = (lane < 8) ? s_keys[par][lane] : 0ULL;
#pragma unroll
            for (int off = 1; off < 8; off <<= 1) {
                unsigned long long ok = __shfl_xor(bk, off, 8);
                if (ok > bk) bk = ok;
            }
            if (lane == 0)
                __hip_atomic_store(&sl[g], bk, __ATOMIC_RELAXED, __HIP_MEMORY_SCOPE_AGENT);
        }
        asm volatile("" ::: "memory");
        unsigned long long kk = 0ULL;
        while (true) {
            if (lane < NSLOT && kk == 0ULL)
                kk = __hip_atomic_load(&sl[lane], __ATOMIC_RELAXED,
                                       __HIP_MEMORY_SCOPE_AGENT);
            if (__all(kk != 0ULL || lane >= NSLOT)) break;
        }
        asm volatile("" ::: "memory");
#pragma unroll
        for (int off = 1; off < 8; off <<= 1) {
            unsigned long long ok = __shfl_xor(kk, off, 8);
            if (ok > kk) kk = ok;
        }
        kk = __shfl(kk, 0, 64);   // broadcast winner to all 64 lanes

        int widx = (int)(~(unsigned int)kk);
        float4 qw = P4[widx];
        cx = qw.x; cy = qw.y; cz = qw.z;
        if (g == 0 && t == 0) {
            float* sd = seedxyz + ((size_t)bc * SMAX + s) * 3;
            sd[0] = cx; sd[1] = cy; sd[2] = cz;
        }
    }
}

// Kernel C: 512-thread block owns 128 points (2 per lane). Pass 1: wave w handles
// classes {w, w+8}; per live class it computes gd from re-derived pv (vmask gates the
// discrete decision; pv itself is continuous) and caches e=exp(10*w*gd) in E[130][128]
// (1.0 for invalid points of live classes: exp(0)=1 exactly). Pass 2 (rows kk==w mod 8)
// is a pure LDS read + mul + float2 store: no d2f/exp recompute.
__global__ __launch_bounds__(OUT_T) void k_out(
    const float* __restrict__ logits, const float4* __restrict__ xyzw,
    const unsigned short* __restrict__ vmask,
    const int* __restrict__ nseeds, const float* __restrict__ seedxyz,
    float* __restrict__ out, int N) {
    int b = blockIdx.y;
    int t = threadIdx.x;
    int lane = t & 63;
    int wv = t >> 6;         // wave 0..7
    int n0 = blockIdx.x * 128 + lane * 2;
    int l2 = lane * 2;

    __shared__ float S[NCLS * SMAX * 3];
    __shared__ int NSs[NCLS];
    __shared__ float psum[8][128];
    __shared__ float E[NCLS * SMAX][128];
    if (t < NCLS * SMAX * 3) S[t] = seedxyz[(size_t)b * NCLS * SMAX * 3 + t];
    if (t >= 448 && t < 448 + NCLS) NSs[t - 448] = nseeds[b * NCLS + (t - 448)];
    __syncthreads();

    size_t bn0 = (size_t)b * N + n0;
    float4 q0 = xyzw[bn0];
    float4 q1 = xyzw[bn0 + 1];
    unsigned int vm0 = vmask[bn0];
    unsigned int vm1 = vmask[bn0 + 1];

    // softmax denominators (continuous path only; validity gate comes from vmask)
    const float* L0 = logits + bn0 * NCLS;
    const float* L1 = L0 + NCLS;
    float mx0 = -INFINITY, mx1 = -INFINITY;
#pragma unroll
    for (int c = 0; c < NCLS; ++c) {
        mx0 = fmaxf(mx0, L0[c]);
        mx1 = fmaxf(mx1, L1[c]);
    }
    float dn0 = 0.f, dn1 = 0.f;
#pragma unroll
    for (int c = 0; c < NCLS; ++c) {
        dn0 += __expf(L0[c] - mx0);
        dn1 += __expf(L1[c] - mx1);
    }
    float rd0 = __fdividef(1.f, dn0);
    float rd1 = __fdividef(1.f, dn1);

    const float kinv = 22.2222222f;   // 1/0.045
    float ps0 = 0.f, ps1 = 0.f;
    for (int c = wv; c < NCLS; c += 8) {
        int ns = NSs[c];
        if (ns == 0) continue;
        // point 0
        if ((vm0 >> c) & 1) {
            float pv = __expf(L0[c] - mx0) * rd0;
            float wb[SMAX]; float sw = 0.f;
#pragma unroll
            for (int s = 0; s < SMAX; ++s) {
                wb[s] = 0.f;
                if (s < ns) {
                    const float* sd = &S[(c * SMAX + s) * 3];
                    float d2 = d2f(q0.x, q0.y, q0.z, sd[0], sd[1], sd[2]);
                    wb[s] = __expf(-d2 * kinv);
                    sw += wb[s];
                }
            }
            float gd = __fdividef(pv, sw + 1e-8f);
#pragma unroll
            for (int s = 0; s < SMAX; ++s)
                if (s < ns) {
                    float e = __expf(10.f * wb[s] * gd);
                    E[c * SMAX + s][l2] = e;
                    ps0 += e;
                }
        } else {
#pragma unroll
            for (int s = 0; s < SMAX; ++s)
                if (s < ns) E[c * SMAX + s][l2] = 1.0f;
            ps0 += (float)ns;   // exp(0)=1 per valid seed, exact
        }
        // point 1
        if ((vm1 >> c) & 1) {
            float pv = __expf(L1[c] - mx1) * rd1;
            float wb[SMAX]; float sw = 0.f;
#pragma unroll
            for (int s = 0; s < SMAX; ++s) {
                wb[s] = 0.f;
                if (s < ns) {
                    const float* sd = &S[(c * SMAX + s) * 3];
                    float d2 = d2f(q1.x, q1.y, q1.z, sd[0], sd[1], sd[2]);
                    wb[s] = __expf(-d2 * kinv);
                    sw += wb[s];
                }
            }
            float gd = __fdividef(pv, sw + 1e-8f);
#pragma unroll
            for (int s = 0; s < SMAX; ++s)
                if (s < ns) {
                    float e = __expf(10.f * wb[s] * gd);
                    E[c * SMAX + s][l2 + 1] = e;
                    ps1 += e;
                }
        } else {
#pragma unroll
            for (int s = 0; s < SMAX; ++s)
                if (s < ns) E[c * SMAX + s][l2 + 1] = 1.0f;
            ps1 += (float)ns;
        }
    }
    psum[wv][l2] = ps0;
    psum[wv][l2 + 1] = ps1;
    __syncthreads();

    float tot0 = 0.f, tot1 = 0.f;
#pragma unroll
    for (int w = 0; w < 8; ++w) {
        tot0 += psum[w][l2];
        tot1 += psum[w][l2 + 1];
    }
    float inv0 = __fdividef(1.f, tot0);
    float inv1 = __fdividef(1.f, tot1);

    float* ob = out + (size_t)b * (NCLS * SMAX) * N + n0;
    for (int kk = wv; kk < NCLS * SMAX; kk += 8) {
        int c = kk / SMAX, s = kk - c * SMAX;
        float2 o; o.x = 0.f; o.y = 0.f;
        if (s < NSs[c]) {
            o.x = E[kk][l2] * inv0;
            o.y = E[kk][l2 + 1] * inv1;
        }
        *(float2*)(ob + (size_t)kk * N) = o;
    }
}

extern "C" void kernel_launch(void* const* d_in, const int* in_sizes, int n_in,
                              void* d_out, int out_size, void* d_ws, size_t ws_size,
                              hipStream_t stream) {
    const float* logits = (const float*)d_in[0];
    const float* pts    = (const float*)d_in[1];
    const float* offs   = (const float*)d_in[2];
    float* out = (float*)d_out;

    const int B = BB;
    const int BN = in_sizes[0] / NCLS;   // B*N
    const int N = BN / B;                // 65536

    // Workspace layout
    char* w = (char*)d_ws;
    size_t off = 0;
    auto take = [&](size_t bytes) -> void* {
        void* p = w + off;
        off = (off + bytes + 255) & ~(size_t)255;
        return p;
    };
    float4* xyzw   = (float4*)take((size_t)B * N * sizeof(float4));
    unsigned short* vmsk = (unsigned short*)take((size_t)B * N * sizeof(unsigned short));
    float* seedxyz = (float*)take((size_t)B * NCLS * SMAX * 3 * sizeof(float));
    unsigned int* pcnt = (unsigned int*)take((size_t)B * NCLS * GABLK * sizeof(unsigned int));
    unsigned int* pfst = (unsigned int*)take((size_t)B * NCLS * GABLK * sizeof(unsigned int));
    int* nseeds        = (int*)take(B * NCLS * sizeof(int));
    unsigned long long* slots =
        (unsigned long long*)take((size_t)B * NCLS * SMAX * NSLOT * sizeof(unsigned long long));

    dim3 gA((N + 255) / 256, B);   // == (GABLK, B)
    k_setup<<<gA, 256, 0, stream>>>(logits, pts, offs, xyzw, vmsk,
                                    pcnt, pfst, (unsigned int*)slots, N);

    k_fps<<<BCPAD * FPS_SEG, FPS_T, 0, stream>>>(xyzw, vmsk, pcnt, pfst,
                                                 nseeds, seedxyz, slots, N);

    dim3 gC(N / 128, B);
    k_out<<<gC, OUT_T, 0, stream>>>(logits, xyzw, vmsk, nseeds, seedxyz, out, N);
}

// Round 13
// 56.354 us; speedup vs baseline: 1.2496x; 1.1423x over previous
//
#include <hip/hip_runtime.h>
#include <cstdint>

#define NCLS 13
#define SMAX 10
#define PTHRESH 0.05f
#define FPS_SEG 8        // blocks per (b,c)
#define FPS_T 512        // threads per FPS block (8 waves)
#define FPS_PPT 16       // points per thread: 8*512*16 = 65536
#define NSLOT 8          // one record per block per step
#define BCPAD 32         // padded bc dim: all 8 blocks of a bc share bid%32
#define GABLK 256        // k_setup blocks per batch (N/256)
#define BB 2             // batch
#define OUT_T 512        // k_out threads (8 waves, 128-point tile, 2 pts/lane)
#define SLOT_DWORDS (BB * NCLS * SMAX * NSLOT * 2)

// Exact (un-fused) squared distance, matching numpy's ((dx*dx + dy*dy) + dz*dz) in f32.
__device__ __forceinline__ float d2f(float ax, float ay, float az,
                                     float bx, float by, float bz) {
    float dx = ax - bx;
    float dy = ay - by;
    float dz = az - bz;
    return __fadd_rn(__fadd_rn(__fmul_rn(dx, dx), __fmul_rn(dy, dy)), __fmul_rn(dz, dz));
}

// Monotone mapping float -> uint32. Never 0 for non-NaN input => key==0 means "empty".
__device__ __forceinline__ unsigned int fmono(float f) {
    unsigned int u = __float_as_uint(f);
    return (u & 0x80000000u) ? ~u : (u | 0x80000000u);
}

// bf16 encode (round-half-up; e in [1, 2.2e4], rel err ~2^-9) / decode
__device__ __forceinline__ unsigned short bf16e(float f) {
    return (unsigned short)((__float_as_uint(f) + 0x8000u) >> 16);
}
__device__ __forceinline__ float bf16d(unsigned short u) {
    return __uint_as_float((unsigned int)u << 16);
}

// Kernel A: class softmax (accurate expf -> discrete decisions), packed coords (float4),
// per-point class-validity bitmask (u16), per-block partial counts/first-index, slot
// zeroing. probs are NOT materialized (k_out re-derives pv; k_fps uses vmask only).
__global__ void k_setup(const float* __restrict__ logits, const float* __restrict__ pts,
                        const float* __restrict__ offs,
                        float4* __restrict__ xyzw, unsigned short* __restrict__ vmask,
                        unsigned int* __restrict__ pcnt, unsigned int* __restrict__ pfst,
                        unsigned int* __restrict__ slots32, int N) {
    int b = blockIdx.y;
    int n = blockIdx.x * blockDim.x + threadIdx.x;
    int t = threadIdx.x;
    __shared__ unsigned int sC[NCLS], sF[NCLS];
    if (t < NCLS) { sC[t] = 0u; sF[t] = 0xFFFFFFFFu; }
    __syncthreads();

    // zero FPS slots (every call: graph replays leave stale nonzero keys behind)
    if (b == 0) {
        for (unsigned int i = blockIdx.x * blockDim.x + t; i < SLOT_DWORDS;
             i += GABLK * 256)
            slots32[i] = 0u;
    }

    if (n < N) {
        size_t bn = (size_t)b * N + n;
        const float* L = logits + bn * NCLS;
        float v[NCLS];
        float mx = -INFINITY;
#pragma unroll
        for (int c = 0; c < NCLS; ++c) { v[c] = L[c]; mx = fmaxf(mx, v[c]); }
        float s = 0.f;
#pragma unroll
        for (int c = 0; c < NCLS; ++c) { v[c] = expf(v[c] - mx); s += v[c]; }
        int lane = t & 63;
        int wave_base = n - lane;
        unsigned int msk = 0;
#pragma unroll
        for (int c = 0; c < NCLS; ++c) {
            float p = v[c] / s;
            bool valid = p > PTHRESH;
            if (valid) msk |= (1u << c);
            unsigned long long m = __ballot(valid);
            if (lane == 0 && m) {
                atomicAdd(&sC[c], (unsigned int)__popcll(m));
                atomicMin(&sF[c], (unsigned int)(wave_base + __ffsll(m) - 1));
            }
        }
        float x = pts[bn * 3 + 0] + offs[bn * 3 + 0];
        float y = pts[bn * 3 + 1] + offs[bn * 3 + 1];
        float z = pts[bn * 3 + 2] + offs[bn * 3 + 2];
        xyzw[bn] = make_float4(x, y, z, 0.f);
        vmask[bn] = (unsigned short)msk;
    }
    __syncthreads();
    if (t < NCLS) {
        pcnt[(b * NCLS + t) * GABLK + blockIdx.x] = sC[t];
        pfst[(b * NCLS + t) * GABLK + blockIdx.x] = sF[t];
    }
}

// Kernel B: deterministic FPS (round-9 config — measured best). 8 blocks x 512 threads
// per (b,c). Per step (ONE barrier): wave butterfly argmax -> s_keys[parity] -> barrier
// -> wave0 reduces 8 keys, lane0 publishes block record -> ALL waves poll the 8-slot
// line (8-lane coalesced relaxed load) -> butterfly-8 + broadcast -> winner coords
// from immutable xyzw (single dwordx4).
__global__ __launch_bounds__(FPS_T, 1) void k_fps(
    const float4* __restrict__ xyzw, const unsigned short* __restrict__ vmask,
    const unsigned int* __restrict__ pcnt, const unsigned int* __restrict__ pfst,
    int* __restrict__ nseeds, float* __restrict__ seedxyz,
    unsigned long long* __restrict__ slots, int N) {
    int bid = blockIdx.x;
    int bc = bid & (BCPAD - 1);
    int g = bid >> 5;             // segment 0..7
    if (bc >= BB * NCLS) return;  // padding blocks
    int b = bc / NCLS;
    int c = bc - b * NCLS;
    int t = threadIdx.x, lane = t & 63, w = t >> 6;

    // Reduce per-block partials (each wave redundantly; identical ops -> identical result)
    const unsigned int* pc = pcnt + (size_t)bc * GABLK;
    const unsigned int* pf = pfst + (size_t)bc * GABLK;
    uint4 c4 = *(const uint4*)(pc + lane * 4);
    uint4 f4 = *(const uint4*)(pf + lane * 4);
    unsigned int cnt = c4.x + c4.y + c4.z + c4.w;
    unsigned int fst = min(min(f4.x, f4.y), min(f4.z, f4.w));
#pragma unroll
    for (int off = 1; off < 64; off <<= 1) {
        cnt += __shfl_xor(cnt, off, 64);
        fst = min(fst, __shfl_xor(fst, off, 64));
    }
    int ns = min(SMAX, min((int)cnt / 50, (int)cnt));
    if (g == 0 && t == 0) nseeds[bc] = ns;
    if (ns == 0) return;

    const float4* P4 = xyzw + (size_t)b * N;
    const unsigned short* VM = vmask + (size_t)b * N;

    int base = g * (FPS_T * FPS_PPT) + t;
    float X[FPS_PPT], Y[FPS_PPT], Z[FPS_PPT], m[FPS_PPT];
    unsigned int vm = 0;
#pragma unroll
    for (int j = 0; j < FPS_PPT; ++j) {
        int n = base + (j << 9);
        float4 q = P4[n];
        X[j] = q.x; Y[j] = q.y; Z[j] = q.z;
        if ((VM[n] >> c) & 1) vm |= (1u << j);
        m[j] = INFINITY;
    }

    int st = (int)fst;
    float4 q0 = P4[st];
    float cx = q0.x, cy = q0.y, cz = q0.z;
    if (g == 0 && t == 0) {
        float* sd = seedxyz + (size_t)bc * SMAX * 3;
        sd[0] = cx; sd[1] = cy; sd[2] = cz;
    }

    __shared__ unsigned long long s_keys[2][FPS_T / 64];

    for (int s = 1; s < ns; ++s) {
        float best = -INFINITY;
        int bidx = 0;
#pragma unroll
        for (int j = 0; j < FPS_PPT; ++j) {   // ascending n => first-occurrence tiebreak
            int n = base + (j << 9);
            float d2 = d2f(X[j], Y[j], Z[j], cx, cy, cz);
            float add = ((vm >> j) & 1u) ? 0.0f : -INFINITY;
            float nm = fminf(m[j], __fadd_rn(d2, add));
            m[j] = nm;
            if (nm > best) { best = nm; bidx = n; }
        }
        unsigned long long key =
            ((unsigned long long)fmono(best) << 32) | (unsigned int)(~(unsigned int)bidx);
#pragma unroll
        for (int off = 1; off < 64; off <<= 1) {
            unsigned long long ok = __shfl_xor(key, off, 64);
            if (ok > key) key = ok;
        }
        int par = s & 1;
        if (lane == 0) s_keys[par][w] = key;
        __syncthreads();

        unsigned long long* sl = slots + ((size_t)bc * SMAX + s) * NSLOT;
        if (w == 0) {
            unsigned long long bk = (lane < 8) ? s_keys[par][lane] : 0ULL;
#pragma unroll
            for (int off = 1; off < 8; off <<= 1) {
                unsigned long long ok = __shfl_xor(bk, off, 8);
                if (ok > bk) bk = ok;
            }
            if (lane == 0)
                __hip_atomic_store(&sl[g], bk, __ATOMIC_RELAXED, __HIP_MEMORY_SCOPE_AGENT);
        }
        asm volatile("" ::: "memory");
        unsigned long long kk = 0ULL;
        while (true) {
            if (lane < NSLOT && kk == 0ULL)
                kk = __hip_atomic_load(&sl[lane], __ATOMIC_RELAXED,
                                       __HIP_MEMORY_SCOPE_AGENT);
            if (__all(kk != 0ULL || lane >= NSLOT)) break;
        }
        asm volatile("" ::: "memory");
#pragma unroll
        for (int off = 1; off < 8; off <<= 1) {
            unsigned long long ok = __shfl_xor(kk, off, 8);
            if (ok > kk) kk = ok;
        }
        kk = __shfl(kk, 0, 64);   // broadcast winner to all 64 lanes

        int widx = (int)(~(unsigned int)kk);
        float4 qw = P4[widx];
        cx = qw.x; cy = qw.y; cz = qw.z;
        if (g == 0 && t == 0) {
            float* sd = seedxyz + ((size_t)bc * SMAX + s) * 3;
            sd[0] = cx; sd[1] = cy; sd[2] = cz;
        }
    }
}

// Kernel C: 512-thread block owns 128 points (2 per lane). Pass 1: wave w handles
// classes {w, w+8}; computes gd from re-derived pv (vmask gates the discrete decision)
// and caches e=exp(10*w*gd) as BF16 in E[130][128] (33 KB -> 4 blocks/CU; sumexp
// accumulates the f32 e, so only the stored/re-read value is quantized ~0.2%).
// Pass 2 (rows kk==w mod 8): pure LDS read + mul + NONTEMPORAL float2 store (output
// is write-once, never re-read -> keep it out of L2).
__global__ __launch_bounds__(OUT_T) void k_out(
    const float* __restrict__ logits, const float4* __restrict__ xyzw,
    const unsigned short* __restrict__ vmask,
    const int* __restrict__ nseeds, const float* __restrict__ seedxyz,
    float* __restrict__ out, int N) {
    int b = blockIdx.y;
    int t = threadIdx.x;
    int lane = t & 63;
    int wv = t >> 6;         // wave 0..7
    int n0 = blockIdx.x * 128 + lane * 2;
    int l2 = lane * 2;

    __shared__ float S[NCLS * SMAX * 3];
    __shared__ int NSs[NCLS];
    __shared__ float psum[8][128];
    __shared__ unsigned short E[NCLS * SMAX][128];
    if (t < NCLS * SMAX * 3) S[t] = seedxyz[(size_t)b * NCLS * SMAX * 3 + t];
    if (t >= 448 && t < 448 + NCLS) NSs[t - 448] = nseeds[b * NCLS + (t - 448)];
    __syncthreads();

    size_t bn0 = (size_t)b * N + n0;
    float4 q0 = xyzw[bn0];
    float4 q1 = xyzw[bn0 + 1];
    unsigned int vm0 = vmask[bn0];
    unsigned int vm1 = vmask[bn0 + 1];

    // softmax denominators (continuous path only; validity gate comes from vmask)
    const float* L0 = logits + bn0 * NCLS;
    const float* L1 = L0 + NCLS;
    float mx0 = -INFINITY, mx1 = -INFINITY;
#pragma unroll
    for (int c = 0; c < NCLS; ++c) {
        mx0 = fmaxf(mx0, L0[c]);
        mx1 = fmaxf(mx1, L1[c]);
    }
    float dn0 = 0.f, dn1 = 0.f;
#pragma unroll
    for (int c = 0; c < NCLS; ++c) {
        dn0 += __expf(L0[c] - mx0);
        dn1 += __expf(L1[c] - mx1);
    }
    float rd0 = __fdividef(1.f, dn0);
    float rd1 = __fdividef(1.f, dn1);

    const float kinv = 22.2222222f;   // 1/0.045
    float ps0 = 0.f, ps1 = 0.f;
    for (int c = wv; c < NCLS; c += 8) {
        int ns = NSs[c];
        if (ns == 0) continue;
        // point 0
        if ((vm0 >> c) & 1) {
            float pv = __expf(L0[c] - mx0) * rd0;
            float wb[SMAX]; float sw = 0.f;
#pragma unroll
            for (int s = 0; s < SMAX; ++s) {
                wb[s] = 0.f;
                if (s < ns) {
                    const float* sd = &S[(c * SMAX + s) * 3];
                    float d2 = d2f(q0.x, q0.y, q0.z, sd[0], sd[1], sd[2]);
                    wb[s] = __expf(-d2 * kinv);
                    sw += wb[s];
                }
            }
            float gd = __fdividef(pv, sw + 1e-8f);
#pragma unroll
            for (int s = 0; s < SMAX; ++s)
                if (s < ns) {
                    float e = __expf(10.f * wb[s] * gd);
                    E[c * SMAX + s][l2] = bf16e(e);
                    ps0 += e;
                }
        } else {
#pragma unroll
            for (int s = 0; s < SMAX; ++s)
                if (s < ns) E[c * SMAX + s][l2] = 0x3F80;   // bf16(1.0)
            ps0 += (float)ns;   // exp(0)=1 per valid seed, exact
        }
        // point 1
        if ((vm1 >> c) & 1) {
            float pv = __expf(L1[c] - mx1) * rd1;
            float wb[SMAX]; float sw = 0.f;
#pragma unroll
            for (int s = 0; s < SMAX; ++s) {
                wb[s] = 0.f;
                if (s < ns) {
                    const float* sd = &S[(c * SMAX + s) * 3];
                    float d2 = d2f(q1.x, q1.y, q1.z, sd[0], sd[1], sd[2]);
                    wb[s] = __expf(-d2 * kinv);
                    sw += wb[s];
                }
            }
            float gd = __fdividef(pv, sw + 1e-8f);
#pragma unroll
            for (int s = 0; s < SMAX; ++s)
                if (s < ns) {
                    float e = __expf(10.f * wb[s] * gd);
                    E[c * SMAX + s][l2 + 1] = bf16e(e);
                    ps1 += e;
                }
        } else {
#pragma unroll
            for (int s = 0; s < SMAX; ++s)
                if (s < ns) E[c * SMAX + s][l2 + 1] = 0x3F80;
            ps1 += (float)ns;
        }
    }
    psum[wv][l2] = ps0;
    psum[wv][l2 + 1] = ps1;
    __syncthreads();

    float tot0 = 0.f, tot1 = 0.f;
#pragma unroll
    for (int w = 0; w < 8; ++w) {
        tot0 += psum[w][l2];
        tot1 += psum[w][l2 + 1];
    }
    float inv0 = __fdividef(1.f, tot0);
    float inv1 = __fdividef(1.f, tot1);

    float* ob = out + (size_t)b * (NCLS * SMAX) * N + n0;
    for (int kk = wv; kk < NCLS * SMAX; kk += 8) {
        int c = kk / SMAX, s = kk - c * SMAX;
        float2 o; o.x = 0.f; o.y = 0.f;
        if (s < NSs[c]) {
            o.x = bf16d(E[kk][l2]) * inv0;
            o.y = bf16d(E[kk][l2 + 1]) * inv1;
        }
        union { float2 f; unsigned long long u; } cvt;
        cvt.f = o;
        __builtin_nontemporal_store(cvt.u,
            (unsigned long long*)(ob + (size_t)kk * N));
    }
}

extern "C" void kernel_launch(void* const* d_in, const int* in_sizes, int n_in,
                              void* d_out, int out_size, void* d_ws, size_t ws_size,
                              hipStream_t stream) {
    const float* logits = (const float*)d_in[0];
    const float* pts    = (const float*)d_in[1];
    const float* offs   = (const float*)d_in[2];
    float* out = (float*)d_out;

    const int B = BB;
    const int BN = in_sizes[0] / NCLS;   // B*N
    const int N = BN / B;                // 65536

    // Workspace layout
    char* w = (char*)d_ws;
    size_t off = 0;
    auto take = [&](size_t bytes) -> void* {
        void* p = w + off;
        off = (off + bytes + 255) & ~(size_t)255;
        return p;
    };
    float4* xyzw   = (float4*)take((size_t)B * N * sizeof(float4));
    unsigned short* vmsk = (unsigned short*)take((size_t)B * N * sizeof(unsigned short));
    float* seedxyz = (float*)take((size_t)B * NCLS * SMAX * 3 * sizeof(float));
    unsigned int* pcnt = (unsigned int*)take((size_t)B * NCLS * GABLK * sizeof(unsigned int));
    unsigned int* pfst = (unsigned int*)take((size_t)B * NCLS * GABLK * sizeof(unsigned int));
    int* nseeds        = (int*)take(B * NCLS * sizeof(int));
    unsigned long long* slots =
        (unsigned long long*)take((size_t)B * NCLS * SMAX * NSLOT * sizeof(unsigned long long));

    dim3 gA((N + 255) / 256, B);   // == (GABLK, B)
    k_setup<<<gA, 256, 0, stream>>>(logits, pts, offs, xyzw, vmsk,
                                    pcnt, pfst, (unsigned int*)slots, N);

    k_fps<<<BCPAD * FPS_SEG, FPS_T, 0, stream>>>(xyzw, vmsk, pcnt, pfst,
                                                 nseeds, seedxyz, slots, N);

    dim3 gC(N / 128, B);
    k_out<<<gC, OUT_T, 0, stream>>>(logits, xyzw, vmsk, nseeds, seedxyz, out, N);
}